// Round 4
// baseline (357.993 us; speedup 1.0000x reference)
//
#include <hip/hip_runtime.h>

typedef unsigned short u16;
typedef unsigned int u32;

typedef __bf16 v8bf __attribute__((ext_vector_type(8)));
typedef float v4f __attribute__((ext_vector_type(4)));
typedef u16 v8u __attribute__((ext_vector_type(8)));

#define N_TOK 8192
#define CDIM 512
#define HEADS 8
#define HD 64
#define LM 64
#define LSTRIDE 128
#define BHN 32
#define NCHUNK 16
#define SCALE 0.125f

__device__ __forceinline__ float b2f(u16 u) { return __uint_as_float(((u32)u) << 16); }
__device__ __forceinline__ u16 f2bf(float f) {
  u32 u = __float_as_uint(f);
  u += 0x7fffu + ((u >> 16) & 1u);
  return (u16)(u >> 16);
}
__device__ __forceinline__ u32 pk2bf(float a, float b) {
  return (u32)f2bf(a) | ((u32)f2bf(b) << 16);
}

// async global->LDS, 16B per lane. HW dest = wave-uniform base + lane*16.
__device__ __forceinline__ void gl_lds16(const u16* g, u16* l) {
  __builtin_amdgcn_global_load_lds(
      (const __attribute__((address_space(1))) u32*)g,
      (__attribute__((address_space(3))) u32*)l, 16, 0, 0);
}

// ---------------------------------------------------------------------------
// fp32 -> bf16 cast, 8 elems/thread, fully coalesced.
// ---------------------------------------------------------------------------
__global__ __launch_bounds__(256) void cast_bf16(const float* __restrict__ src,
                                                 u16* __restrict__ dst, int n8) {
  int i = blockIdx.x * 256 + threadIdx.x;
  if (i >= n8) return;
  const float4* s = (const float4*)src;
  float4 a = s[(size_t)i * 2], b = s[(size_t)i * 2 + 1];
  uint4 o;
  o.x = (u32)f2bf(a.x) | ((u32)f2bf(a.y) << 16);
  o.y = (u32)f2bf(a.z) | ((u32)f2bf(a.w) << 16);
  o.z = (u32)f2bf(b.x) | ((u32)f2bf(b.y) << 16);
  o.w = (u32)f2bf(b.z) | ((u32)f2bf(b.w) << 16);
  *(uint4*)(dst + (size_t)i * 8) = o;
}

// ---------------------------------------------------------------------------
// GEMM R9: 256x256, BK=64, 512 thr (8 waves: wm=w>>2 over 128 rows, wn=w&3
// over 64 cols). 4 fat phases per K-tile, 16 MFMA each; one 2-granule stage
// pair per phase, stream 5 phases ahead of consumption -> boundary wait is
// vmcnt(6) = 3 pairs in flight, NEVER a drain (T3+T4). setprio on MFMA (T5).
//
// LDS [2][256][64] bf16 per operand (128 KiB, 1 block/CU). Granule g = rows
// 64g..64g+63 (8 KiB = 512 thr x 16B, linear dest). Involution swizzle:
// chunk slot = c ^ (row&7) on BOTH the DMA global source and the ds_read
// (rule #21). Bank check: per 16-lane quarter-wave, 8 slots x 2 lanes
// (rows l3, l3+8) = 2-way same-bank = free (m136).
//
// Region liveness (reads: A granule {wm*2+mh} read in phase mh; B granule
// {wn} read in phases 0 (nh0) and 1 (nh1)):
//   S.p0 stages B2B3(S+1)  -> other buf; last read S-1.p1  (>=3 bars ago)
//   S.p1 stages A0A2(S+2)  -> cur buf;  granules 0,2 read in S.p0 (done)
//   S.p2 stages B0B1(S+2)  -> cur buf;  read in S.p0/p1 (done)
//   S.p3 stages A1A3(S+2)  -> cur buf;  granules 1,3 read in S.p2 (done)
// Boundary before S.p0: tile-S calls are all older than the newest 6
// (A0A2,B0B1,A1A3 of S+1) -> vmcnt(6) + s_barrier proves tile S landed.
// ---------------------------------------------------------------------------
template <int MODE>
__global__ __launch_bounds__(512, 2) void gemm_bt(const u16* __restrict__ A,
                                                  const u16* __restrict__ Bm,
                                                  const float* __restrict__ bias,
                                                  u16* __restrict__ qo,
                                                  u16* __restrict__ ko,
                                                  u16* __restrict__ vo,
                                                  float* __restrict__ outp) {
  __shared__ __align__(16) u16 Al[32768];
  __shared__ __align__(16) u16 Bl[32768];
  const int K = 512;
  const int NT = 8;  // K / 64
  const int m0 = blockIdx.x * 256;
  const int n0 = blockIdx.y * 256;
  const int t = threadIdx.x;
  const int lane = t & 63, w = t >> 6;
  const int wm = w >> 2, wn = w & 3;
  const int quad = lane >> 4, lrow = lane & 15;
  const int l3 = lrow & 7;

  const int srl = t >> 3;
  const int gch = ((t & 7) ^ (srl & 7)) * 8;  // inverse-swizzled source chunk

#define STA(g, tt)                                                            \
  gl_lds16(A + (size_t)(m0 + (g) * 64 + srl) * K + (tt) * 64 + gch,           \
           &Al[((tt) & 1) * 16384 + (g) * 4096 + t * 8])
#define STB(g, tt)                                                            \
  gl_lds16(Bm + (size_t)(n0 + (g) * 64 + srl) * K + (tt) * 64 + gch,          \
           &Bl[((tt) & 1) * 16384 + (g) * 4096 + t * 8])

  v4f acc[8][4];
#pragma unroll
  for (int i = 0; i < 8; ++i)
#pragma unroll
    for (int j = 0; j < 4; ++j)
#pragma unroll
      for (int r = 0; r < 4; ++r) acc[i][j][r] = 0.f;

  // prologue stream: A0A2(0) B0B1(0) A1A3(0) B2B3(0) A0A2(1) B0B1(1) A1A3(1)
  STA(0, 0); STA(2, 0); STB(0, 0); STB(1, 0); STA(1, 0); STA(3, 0);
  STB(2, 0); STB(3, 0);
  STA(0, 1); STA(2, 1); STB(0, 1); STB(1, 1); STA(1, 1); STA(3, 1);

  v8bf af[4][2], b0[2][2], b1[2][2];
  for (int S = 0; S < NT; ++S) {
    const int bu = S & 1;
    const u16* Ab = &Al[bu * 16384];
    const u16* Bb = &Bl[bu * 16384];
    asm volatile("s_waitcnt vmcnt(6)" ::: "memory");
    __builtin_amdgcn_s_barrier();
    __builtin_amdgcn_sched_barrier(0);
    // ---- p0: (mh0,nh0) | stage B2B3(S+1) ----
#pragma unroll
    for (int fm = 0; fm < 4; ++fm)
#pragma unroll
      for (int kk = 0; kk < 2; ++kk)
        af[fm][kk] = *(const v8bf*)&Ab[(wm * 128 + fm * 16 + lrow) * 64 +
                                       (((kk * 4 + quad) ^ l3) * 8)];
#pragma unroll
    for (int fn = 0; fn < 2; ++fn)
#pragma unroll
      for (int kk = 0; kk < 2; ++kk)
        b0[fn][kk] = *(const v8bf*)&Bb[(wn * 64 + fn * 16 + lrow) * 64 +
                                       (((kk * 4 + quad) ^ l3) * 8)];
    if (S + 1 < NT) { STB(2, S + 1); STB(3, S + 1); }
    __builtin_amdgcn_sched_barrier(0);
    __builtin_amdgcn_s_barrier();
    asm volatile("s_waitcnt lgkmcnt(0)" ::: "memory");
    __builtin_amdgcn_sched_barrier(0);
    __builtin_amdgcn_s_setprio(1);
#pragma unroll
    for (int fm = 0; fm < 4; ++fm)
#pragma unroll
      for (int fn = 0; fn < 2; ++fn)
#pragma unroll
        for (int kk = 0; kk < 2; ++kk)
          acc[fm][fn] = __builtin_amdgcn_mfma_f32_16x16x32_bf16(af[fm][kk], b0[fn][kk], acc[fm][fn], 0, 0, 0);
    __builtin_amdgcn_s_setprio(0);
    __builtin_amdgcn_sched_barrier(0);
    __builtin_amdgcn_s_barrier();
    // ---- p1: (mh0,nh1) | stage A0A2(S+2) ----
#pragma unroll
    for (int fn = 0; fn < 2; ++fn)
#pragma unroll
      for (int kk = 0; kk < 2; ++kk)
        b1[fn][kk] = *(const v8bf*)&Bb[(wn * 64 + 32 + fn * 16 + lrow) * 64 +
                                       (((kk * 4 + quad) ^ l3) * 8)];
    if (S + 2 < NT) { STA(0, S + 2); STA(2, S + 2); }
    __builtin_amdgcn_sched_barrier(0);
    __builtin_amdgcn_s_barrier();
    asm volatile("s_waitcnt lgkmcnt(0)" ::: "memory");
    __builtin_amdgcn_sched_barrier(0);
    __builtin_amdgcn_s_setprio(1);
#pragma unroll
    for (int fm = 0; fm < 4; ++fm)
#pragma unroll
      for (int fn = 0; fn < 2; ++fn)
#pragma unroll
        for (int kk = 0; kk < 2; ++kk)
          acc[fm][2 + fn] = __builtin_amdgcn_mfma_f32_16x16x32_bf16(af[fm][kk], b1[fn][kk], acc[fm][2 + fn], 0, 0, 0);
    __builtin_amdgcn_s_setprio(0);
    __builtin_amdgcn_sched_barrier(0);
    __builtin_amdgcn_s_barrier();
    // ---- p2: (mh1,nh0) | stage B0B1(S+2) ----
#pragma unroll
    for (int fm = 0; fm < 4; ++fm)
#pragma unroll
      for (int kk = 0; kk < 2; ++kk)
        af[fm][kk] = *(const v8bf*)&Ab[(wm * 128 + 64 + fm * 16 + lrow) * 64 +
                                       (((kk * 4 + quad) ^ l3) * 8)];
    if (S + 2 < NT) { STB(0, S + 2); STB(1, S + 2); }
    __builtin_amdgcn_sched_barrier(0);
    __builtin_amdgcn_s_barrier();
    asm volatile("s_waitcnt lgkmcnt(0)" ::: "memory");
    __builtin_amdgcn_sched_barrier(0);
    __builtin_amdgcn_s_setprio(1);
#pragma unroll
    for (int fm = 0; fm < 4; ++fm)
#pragma unroll
      for (int fn = 0; fn < 2; ++fn)
#pragma unroll
        for (int kk = 0; kk < 2; ++kk)
          acc[4 + fm][fn] = __builtin_amdgcn_mfma_f32_16x16x32_bf16(af[fm][kk], b0[fn][kk], acc[4 + fm][fn], 0, 0, 0);
    __builtin_amdgcn_s_setprio(0);
    __builtin_amdgcn_sched_barrier(0);
    __builtin_amdgcn_s_barrier();
    // ---- p3: (mh1,nh1) | stage A1A3(S+2); no trailing barrier (loop top) ----
    if (S + 2 < NT) { STA(1, S + 2); STA(3, S + 2); }
    __builtin_amdgcn_sched_barrier(0);
    __builtin_amdgcn_s_setprio(1);
#pragma unroll
    for (int fm = 0; fm < 4; ++fm)
#pragma unroll
      for (int fn = 0; fn < 2; ++fn)
#pragma unroll
        for (int kk = 0; kk < 2; ++kk)
          acc[4 + fm][2 + fn] = __builtin_amdgcn_mfma_f32_16x16x32_bf16(af[fm][kk], b1[fn][kk], acc[4 + fm][2 + fn], 0, 0, 0);
    __builtin_amdgcn_s_setprio(0);
    __builtin_amdgcn_sched_barrier(0);
  }
#undef STA
#undef STB

  // epilogue: D layout col=lane&15, row=quad*4+reg (m89/m91-verified)
#pragma unroll
  for (int mf = 0; mf < 8; ++mf) {
#pragma unroll
    for (int nf = 0; nf < 4; ++nf) {
      int gn = n0 + wn * 64 + nf * 16 + lrow;
      float bv = bias[gn];
#pragma unroll
      for (int r = 0; r < 4; ++r) {
        int gm = m0 + wm * 128 + mf * 16 + quad * 4 + r;
        float val = acc[mf][nf][r] + bv;
        if (MODE == 0) {
          int tt = gn >> 9;          // 0=q 1=k 2=v
          int h = (gn >> 6) & 7;
          int d = gn & 63;
          int b = gm >> 13;
          int n = gm & 8191;
          size_t di = ((size_t)(b * HEADS + h) * N_TOK + n) * HD + d;
          u16* dst = (tt == 0) ? qo : (tt == 1) ? ko : vo;
          dst[di] = f2bf(val);
        } else {
          outp[(size_t)gm * CDIM + gn] = val;
        }
      }
    }
  }
}

// ---------------------------------------------------------------------------
// Fused kernel_3 chunk: full MFMA flash (unchanged from R6).
// ---------------------------------------------------------------------------
__global__ __launch_bounds__(256) void fpart(const u16* __restrict__ qb,
                                             const u16* __restrict__ kb,
                                             const u16* __restrict__ vb,
                                             float* __restrict__ Fp,
                                             float* __restrict__ Mc,
                                             float* __restrict__ Sc) {
  __shared__ __align__(16) char smem[4 * 64 * 40 * 2 * 2];   // 40 KiB
  __shared__ float msh[4][64], ssh[4][64];
  const int jc = blockIdx.x, bh = blockIdx.y;
  const int t = threadIdx.x;
  const int lane = t & 63, w = t >> 6;
  const int col = lane & 15, quad = lane >> 4;
  const int jq = lane & 7, dh = lane >> 3;

  u16* Pw = (u16*)smem + w * (64 * 40);
  u16* vT = (u16*)smem + 4 * (64 * 40) + w * (64 * 40);
  float* Fbuf = (float*)smem;

  v8bf qf[4][2];
#pragma unroll
  for (int it = 0; it < 4; ++it)
#pragma unroll
    for (int kh = 0; kh < 2; ++kh)
      qf[it][kh] = *(const v8bf*)(qb + ((size_t)bh * N_TOK + (size_t)(it * 16 + col) * LSTRIDE) * HD + kh * 32 + quad * 8);

  float mw[4], sw[4];
  v4f facc[4][4];   // facc[dt][it][r] = F[it*16+col][dt*16+quad*4+r]
#pragma unroll
  for (int it = 0; it < 4; ++it) { mw[it] = -3.0e38f; sw[it] = 0.f; }
#pragma unroll
  for (int dt = 0; dt < 4; ++dt)
#pragma unroll
    for (int it = 0; it < 4; ++it)
#pragma unroll
      for (int r = 0; r < 4; ++r) facc[dt][it][r] = 0.f;

  for (int st = 0; st < 4; ++st) {
    const int j0 = jc * 512 + w * 128 + st * 32;

    v8bf kf[2][2];
#pragma unroll
    for (int jt = 0; jt < 2; ++jt)
#pragma unroll
      for (int kh = 0; kh < 2; ++kh)
        kf[jt][kh] = *(const v8bf*)(kb + ((size_t)bh * N_TOK + j0 + jt * 16 + col) * HD + kh * 32 + quad * 8);

    v8u r0 = *(const v8u*)(vb + ((size_t)bh * N_TOK + j0 + jq * 4 + 0) * HD + dh * 8);
    v8u r1 = *(const v8u*)(vb + ((size_t)bh * N_TOK + j0 + jq * 4 + 1) * HD + dh * 8);
    v8u r2 = *(const v8u*)(vb + ((size_t)bh * N_TOK + j0 + jq * 4 + 2) * HD + dh * 8);
    v8u r3 = *(const v8u*)(vb + ((size_t)bh * N_TOK + j0 + jq * 4 + 3) * HD + dh * 8);
#pragma unroll
    for (int e = 0; e < 8; ++e) {
      uint2 pk;
      pk.x = (u32)r0[e] | ((u32)r1[e] << 16);
      pk.y = (u32)r2[e] | ((u32)r3[e] << 16);
      *(uint2*)&vT[(dh * 8 + e) * 40 + jq * 4] = pk;
    }

    v4f sacc[2][4];
#pragma unroll
    for (int jt = 0; jt < 2; ++jt)
#pragma unroll
      for (int it = 0; it < 4; ++it) {
#pragma unroll
        for (int r = 0; r < 4; ++r) sacc[jt][it][r] = 0.f;
#pragma unroll
        for (int kh = 0; kh < 2; ++kh)
          sacc[jt][it] = __builtin_amdgcn_mfma_f32_16x16x32_bf16(kf[jt][kh], qf[it][kh], sacc[jt][it], 0, 0, 0);
      }

#pragma unroll
    for (int it = 0; it < 4; ++it) {
      float mloc = -3.0e38f;
#pragma unroll
      for (int jt = 0; jt < 2; ++jt)
#pragma unroll
        for (int r = 0; r < 4; ++r) {
          float s = sacc[jt][it][r] * SCALE;
          sacc[jt][it][r] = s;
          mloc = fmaxf(mloc, s);
        }
      mloc = fmaxf(mloc, __shfl_xor(mloc, 16));
      mloc = fmaxf(mloc, __shfl_xor(mloc, 32));
      float mnew = fmaxf(mw[it], mloc);
      float alpha = __expf(mw[it] - mnew);
      mw[it] = mnew;
      float rs = 0.f;
#pragma unroll
      for (int jt = 0; jt < 2; ++jt)
#pragma unroll
        for (int r = 0; r < 4; ++r) {
          float p = __expf(sacc[jt][it][r] - mnew);
          sacc[jt][it][r] = p;
          rs += p;
        }
      rs += __shfl_xor(rs, 16);
      rs += __shfl_xor(rs, 32);
      sw[it] = sw[it] * alpha + rs;
#pragma unroll
      for (int jt = 0; jt < 2; ++jt) {
        uint2 pk;
        pk.x = pk2bf(sacc[jt][it][0], sacc[jt][it][1]);
        pk.y = pk2bf(sacc[jt][it][2], sacc[jt][it][3]);
        *(uint2*)&Pw[(it * 16 + col) * 40 + jt * 16 + quad * 4] = pk;
      }
#pragma unroll
      for (int dt = 0; dt < 4; ++dt)
#pragma unroll
        for (int r = 0; r < 4; ++r) facc[dt][it][r] *= alpha;
    }

    v8bf vfr[4], pfr[4];
#pragma unroll
    for (int dt = 0; dt < 4; ++dt)
      vfr[dt] = *(const v8bf*)&vT[(dt * 16 + col) * 40 + quad * 8];
#pragma unroll
    for (int it = 0; it < 4; ++it)
      pfr[it] = *(const v8bf*)&Pw[(it * 16 + col) * 40 + quad * 8];
#pragma unroll
    for (int dt = 0; dt < 4; ++dt)
#pragma unroll
      for (int it = 0; it < 4; ++it)
        facc[dt][it] = __builtin_amdgcn_mfma_f32_16x16x32_bf16(vfr[dt], pfr[it], facc[dt][it], 0, 0, 0);
  }

  if (quad == 0) {
#pragma unroll
    for (int it = 0; it < 4; ++it) {
      msh[w][it * 16 + col] = mw[it];
      ssh[w][it * 16 + col] = sw[it];
    }
  }
  __syncthreads();

  const size_t cb = (size_t)(bh * NCHUNK + jc) * 64;
  float scl[4];
#pragma unroll
  for (int it = 0; it < 4; ++it) {
    int i = it * 16 + col;
    float m0 = msh[0][i], m1 = msh[1][i], m2 = msh[2][i], m3 = msh[3][i];
    float M = fmaxf(fmaxf(m0, m1), fmaxf(m2, m3));
    float e0 = __expf(m0 - M), e1 = __expf(m1 - M);
    float e2 = __expf(m2 - M), e3 = __expf(m3 - M);
    float Stot = e0 * ssh[0][i] + e1 * ssh[1][i] + e2 * ssh[2][i] + e3 * ssh[3][i];
    scl[it] = (w == 0) ? e0 : (w == 1) ? e1 : (w == 2) ? e2 : e3;
    if (w == 0 && quad == 0) {
      Mc[cb + i] = M;
      Sc[cb + i] = Stot;
    }
  }

  for (int wv = 0; wv < 4; ++wv) {
    if (w == wv) {
#pragma unroll
      for (int it = 0; it < 4; ++it)
#pragma unroll
        for (int dt = 0; dt < 4; ++dt) {
          float* dst = &Fbuf[(it * 16 + col) * 76 + dt * 16 + quad * 4];
          float4 v;
          v.x = facc[dt][it][0] * scl[it];
          v.y = facc[dt][it][1] * scl[it];
          v.z = facc[dt][it][2] * scl[it];
          v.w = facc[dt][it][3] * scl[it];
          if (wv == 0) {
            *(float4*)dst = v;
          } else {
            float4 o = *(float4*)dst;
            o.x += v.x; o.y += v.y; o.z += v.z; o.w += v.w;
            *(float4*)dst = o;
          }
        }
    }
    __syncthreads();
  }

  size_t base = (size_t)(bh * NCHUNK + jc) * 4096;
#pragma unroll
  for (int p = 0; p < 16; ++p) {
    int idx = p * 256 + t;
    Fp[base + idx] = Fbuf[(idx >> 6) * 76 + (idx & 63)];
  }
}

// ---------------------------------------------------------------------------
// Per-(b,h): kernel_2 softmax, Newton-Schulz inverse, chunk combine, T = Z@F.
// Epilogue writes Tt = T^T bf16 [bh][d][j] for the MFMA attn_out. (unchanged)
// ---------------------------------------------------------------------------
__global__ __launch_bounds__(256) void newton_t(const u16* __restrict__ qb,
                                                const u16* __restrict__ kb,
                                                const float* __restrict__ Fp,
                                                const float* __restrict__ Mc,
                                                const float* __restrict__ Sc,
                                                u16* __restrict__ Tt) {
  __shared__ float Ms[4096];
  __shared__ float Z0s[4096];
  __shared__ float Ws[4096];
  __shared__ float Xs[4096];
  const int bh = blockIdx.x;
  const int t = threadIdx.x;
  const int lane = t & 63, w = t >> 6;
  const int ti = t >> 4, tj = t & 15;

#pragma unroll
  for (int p = 0; p < 16; ++p) {
    int idx = p * 256 + t;
    int i = idx >> 6, d = idx & 63;
    Ws[idx] = b2f(qb[((size_t)bh * N_TOK + i * LSTRIDE) * HD + d]);
    Xs[d * 64 + i] = b2f(kb[((size_t)bh * N_TOK + i * LSTRIDE) * HD + d]);
  }
  __syncthreads();

  {
    float a2[4][4];
#pragma unroll
    for (int a = 0; a < 4; ++a)
#pragma unroll
      for (int b = 0; b < 4; ++b) a2[a][b] = 0.f;
    for (int d = 0; d < 64; ++d) {
      float qa[4], kv[4];
#pragma unroll
      for (int a = 0; a < 4; ++a) qa[a] = Ws[(ti * 4 + a) * 64 + d];
#pragma unroll
      for (int b = 0; b < 4; ++b) kv[b] = Xs[d * 64 + tj * 4 + b];
#pragma unroll
      for (int a = 0; a < 4; ++a)
#pragma unroll
        for (int b = 0; b < 4; ++b) a2[a][b] += qa[a] * kv[b];
    }
    __syncthreads();
#pragma unroll
    for (int a = 0; a < 4; ++a)
#pragma unroll
      for (int b = 0; b < 4; ++b) Ms[(ti * 4 + a) * 64 + tj * 4 + b] = a2[a][b] * SCALE;
  }
  __syncthreads();

  for (int rr = 0; rr < 16; ++rr) {
    int i = w * 16 + rr;
    float vv = Ms[i * 64 + lane];
    float m = vv;
#pragma unroll
    for (int off = 32; off; off >>= 1) m = fmaxf(m, __shfl_xor(m, off));
    float e = expf(vv - m);
    float s = e;
#pragma unroll
    for (int off = 32; off; off >>= 1) s += __shfl_xor(s, off);
    Ms[i * 64 + lane] = e / s;
  }
  __syncthreads();

  float loc = 0.f;
#pragma unroll
  for (int p = 0; p < 16; ++p) {
    float v = Ms[p * 256 + t];
    loc += v * v;
  }
#pragma unroll
  for (int off = 32; off; off >>= 1) loc += __shfl_xor(loc, off);
  if (lane == 0) Z0s[w] = loc;
  __syncthreads();
  float fro = fmaxf(sqrtf(Z0s[0] + Z0s[1] + Z0s[2] + Z0s[3]), 1e-6f);
  float invden = 1.0f / (fro * fro);
  __syncthreads();

#pragma unroll
  for (int p = 0; p < 16; ++p) {
    int idx = p * 256 + t;
    int i = idx >> 6, j = idx & 63;
    Z0s[j * 64 + i] = Ms[idx] * invden;
  }
  __syncthreads();

  float* Z = Z0s;
  float* Zn = Xs;
  for (int it = 0; it < 6; ++it) {
    {  // Ws = Z @ M
      float a2[4][4];
#pragma unroll
      for (int a = 0; a < 4; ++a)
#pragma unroll
        for (int b = 0; b < 4; ++b) a2[a][b] = 0.f;
      for (int tt = 0; tt < 64; ++tt) {
        float za[4], mb[4];
#pragma unroll
        for (int a = 0; a < 4; ++a) za[a] = Z[(ti * 4 + a) * 64 + tt];
#pragma unroll
        for (int b = 0; b < 4; ++b) mb[b] = Ms[tt * 64 + tj * 4 + b];
#pragma unroll
        for (int a = 0; a < 4; ++a)
#pragma unroll
          for (int b = 0; b < 4; ++b) a2[a][b] += za[a] * mb[b];
      }
#pragma unroll
      for (int a = 0; a < 4; ++a)
#pragma unroll
        for (int b = 0; b < 4; ++b) Ws[(ti * 4 + a) * 64 + tj * 4 + b] = a2[a][b];
    }
    __syncthreads();
    {  // Zn = 2Z - Ws @ Z
      float a2[4][4];
#pragma unroll
      for (int a = 0; a < 4; ++a)
#pragma unroll
        for (int b = 0; b < 4; ++b) a2[a][b] = 0.f;
      for (int tt = 0; tt < 64; ++tt) {
        float wa[4], zb[4];
#pragma unroll
        for (int a = 0; a < 4; ++a) wa[a] = Ws[(ti * 4 + a) * 64 + tt];
#pragma unroll
        for (int b = 0; b < 4; ++b) zb[b] = Z[tt * 64 + tj * 4 + b];
#pragma unroll
        for (int a = 0; a < 4; ++a)
#pragma unroll
          for (int b = 0; b < 4; ++b) a2[a][b] += wa[a] * zb[b];
      }
#pragma unroll
      for (int a = 0; a < 4; ++a)
#pragma unroll
        for (int b = 0; b < 4; ++b)
          Zn[(ti * 4 + a) * 64 + tj * 4 + b] =
              2.f * Z[(ti * 4 + a) * 64 + tj * 4 + b] - a2[a][b];
    }
    __syncthreads();
    float* tmp = Z; Z = Zn; Zn = tmp;
  }

  float* wts = Ms;  // Ms dead -> chunk combine weights [jc][i]
  if (t < 64) {
    float M = -3.0e38f;
#pragma unroll
    for (int jc = 0; jc < NCHUNK; ++jc)
      M = fmaxf(M, Mc[(bh * NCHUNK + jc) * 64 + t]);
    float S = 0.f;
#pragma unroll
    for (int jc = 0; jc < NCHUNK; ++jc)
      S += expf(Mc[(bh * NCHUNK + jc) * 64 + t] - M) * Sc[(bh * NCHUNK + jc) * 64 + t];
    float invS = 1.0f / S;
#pragma unroll
    for (int jc = 0; jc < NCHUNK; ++jc)
      wts[jc * 64 + t] = expf(Mc[(bh * NCHUNK + jc) * 64 + t] - M) * invS;
  }
  __syncthreads();

#pragma unroll
  for (int p = 0; p < 16; ++p) {
    int idx = p * 256 + t;
    int i = idx >> 6;
    float sum = 0.f;
#pragma unroll
    for (int jc = 0; jc < NCHUNK; ++jc)
      sum += wts[jc * 64 + i] * Fp[(size_t)(bh * NCHUNK + jc) * 4096 + idx];
    Ws[idx] = sum;
  }
  __syncthreads();

  {
    float a2[4][4];
#pragma unroll
    for (int a = 0; a < 4; ++a)
#pragma unroll
      for (int b = 0; b < 4; ++b) a2[a][b] = 0.f;
    for (int tt = 0; tt < 64; ++tt) {
      float za[4], fb[4];
#pragma unroll
      for (int a = 0; a < 4; ++a) za[a] = Z[(ti * 4 + a) * 64 + tt];
#pragma unroll
      for (int b = 0; b < 4; ++b) fb[b] = Ws[tt * 64 + tj * 4 + b];
#pragma unroll
      for (int a = 0; a < 4; ++a)
#pragma unroll
        for (int b = 0; b < 4; ++b) a2[a][b] += za[a] * fb[b];
    }
#pragma unroll
    for (int a = 0; a < 4; ++a)
#pragma unroll
      for (int b = 0; b < 4; ++b)
        Tt[(size_t)bh * 4096 + (size_t)(tj * 4 + b) * 64 + (ti * 4 + a)] = f2bf(a2[a][b]);
  }
}

// ---------------------------------------------------------------------------
// MFMA attn_out (unchanged): S^T = klm@q^T, in-register softmax,
// P via per-wave swizzled LDS, out = P@Tt.
// ---------------------------------------------------------------------------
__global__ __launch_bounds__(256) void attn_out_k(const u16* __restrict__ qb,
                                                  const u16* __restrict__ kb,
                                                  const u16* __restrict__ Tt,
                                                  u16* __restrict__ ao) {
  __shared__ __align__(16) u16 Pl[4][1024];
  const int bh = blockIdx.y;
  const int b = bh >> 3, h = bh & 7;
  const int t = threadIdx.x;
  const int lane = t & 63, w = t >> 6;
  const int col = lane & 15, quad = lane >> 4;
  const int rot = (col & 7) * 8;

  v8bf kfr[4][2], tfr[4][2];
#pragma unroll
  for (int tj = 0; tj < 4; ++tj)
#pragma unroll
    for (int kh = 0; kh < 2; ++kh)
      kfr[tj][kh] = *(const v8bf*)(kb + ((size_t)bh * N_TOK + (size_t)(tj * 16 + col) * LSTRIDE) * HD + kh * 32 + quad * 8);
#pragma unroll
  for (int td = 0; td < 4; ++td)
#pragma unroll
    for (int jh = 0; jh < 2; ++jh)
      tfr[td][jh] = *(const v8bf*)(Tt + (size_t)bh * 4096 + (size_t)(td * 16 + col) * 64 + jh * 32 + quad * 8);

  u16* Pw = &Pl[w][0];

  for (int tile = 0; tile < 4; ++tile) {
    const int n0 = blockIdx.x * 256 + w * 64 + tile * 16;
    v8bf qf[2];
#pragma unroll
    for (int kh = 0; kh < 2; ++kh)
      qf[kh] = *(const v8bf*)(qb + ((size_t)bh * N_TOK + n0 + col) * HD + kh * 32 + quad * 8);

    v4f S[4];
#pragma unroll
    for (int tj = 0; tj < 4; ++tj) {
#pragma unroll
      for (int r = 0; r < 4; ++r) S[tj][r] = 0.f;
#pragma unroll
      for (int kh = 0; kh < 2; ++kh)
        S[tj] = __builtin_amdgcn_mfma_f32_16x16x32_bf16(kfr[tj][kh], qf[kh], S[tj], 0, 0, 0);
    }

    float mx = -3.0e38f;
#pragma unroll
    for (int tj = 0; tj < 4; ++tj)
#pragma unroll
      for (int r = 0; r < 4; ++r) {
        S[tj][r] *= SCALE;
        mx = fmaxf(mx, S[tj][r]);
      }
    mx = fmaxf(mx, __shfl_xor(mx, 16));
    mx = fmaxf(mx, __shfl_xor(mx, 32));
    float sum = 0.f;
#pragma unroll
    for (int tj = 0; tj < 4; ++tj)
#pragma unroll
      for (int r = 0; r < 4; ++r) {
        S[tj][r] = __expf(S[tj][r] - mx);
        sum += S[tj][r];
      }
    sum += __shfl_xor(sum, 16);
    sum += __shfl_xor(sum, 32);
    float inv = 1.0f / sum;

#pragma unroll
    for (int tj = 0; tj < 4; ++tj) {
      u32 lo = (u32)f2bf(S[tj][0] * inv) | ((u32)f2bf(S[tj][1] * inv) << 16);
      u32 hi = (u32)f2bf(S[tj][2] * inv) | ((u32)f2bf(S[tj][3] * inv) << 16);
      uint2 pk = {lo, hi};
      *(uint2*)&Pw[col * 64 + ((tj * 16 + quad * 4 + rot) & 63)] = pk;
    }
    v8bf pf[2];
#pragma unroll
    for (int jh = 0; jh < 2; ++jh)
      pf[jh] = *(const v8bf*)&Pw[col * 64 + ((jh * 32 + quad * 8 + rot) & 63)];

    v4f O[4];
#pragma unroll
    for (int td = 0; td < 4; ++td) {
#pragma unroll
      for (int r = 0; r < 4; ++r) O[td][r] = 0.f;
#pragma unroll
      for (int jh = 0; jh < 2; ++jh)
        O[td] = __builtin_amdgcn_mfma_f32_16x16x32_bf16(pf[jh], tfr[td][jh], O[td], 0, 0, 0);
    }
#pragma unroll
    for (int td = 0; td < 4; ++td)
#pragma unroll
      for (int r = 0; r < 4; ++r) {
        int n = n0 + quad * 4 + r;
        ao[((size_t)(b * N_TOK + n)) * CDIM + h * HD + td * 16 + col] = f2bf(O[td][r]);
      }
  }
}

__global__ void ws_too_small_sentinel(float* out) {
  if (threadIdx.x == 0 && blockIdx.x == 0) out[0] = 1.0f;
}

// ---------------------------------------------------------------------------
// Workspace: q/k/v bf16 (96 MiB), Fp fp32 8 MiB, Mc/Sc/Tt small, Wqkv/Wproj
// bf16 casts (+2 MiB). x_bf16 lives in d_out (dead until gemm1). ~107 MiB.
// ---------------------------------------------------------------------------
static constexpr size_t SZ_QKV = (size_t)BHN * N_TOK * HD * 2;        // 32 MiB
static constexpr size_t OFF_Q = 0;
static constexpr size_t OFF_K = OFF_Q + SZ_QKV;
static constexpr size_t OFF_V = OFF_K + SZ_QKV;
static constexpr size_t OFF_FP = OFF_V + SZ_QKV;
static constexpr size_t SZ_FP = (size_t)BHN * NCHUNK * 4096 * 4;      // 8 MiB
static constexpr size_t OFF_MC = OFF_FP + SZ_FP;
static constexpr size_t SZ_MS = (size_t)BHN * NCHUNK * 64 * 4;        // 128 KiB
static constexpr size_t OFF_SC = OFF_MC + SZ_MS;
static constexpr size_t OFF_T = OFF_SC + SZ_MS;
static constexpr size_t OFF_WQ = OFF_T + (size_t)BHN * 4096 * 2;      // Tt 256 KiB
static constexpr size_t OFF_WP = OFF_WQ + (size_t)3 * CDIM * CDIM * 2;  // Wqkv bf16 1.5 MiB
static constexpr size_t OFF_END = OFF_WP + (size_t)CDIM * CDIM * 2;     // +0.5 MiB

extern "C" void kernel_launch(void* const* d_in, const int* in_sizes, int n_in,
                              void* d_out, int out_size, void* d_ws, size_t ws_size,
                              hipStream_t stream) {
  const float* x = (const float*)d_in[0];
  const float* Wqkv = (const float*)d_in[1];
  const float* bqkv = (const float*)d_in[2];
  const float* Wproj = (const float*)d_in[3];
  const float* bproj = (const float*)d_in[4];
  float* out = (float*)d_out;
  char* ws = (char*)d_ws;
  if (ws_size < OFF_END) {
    ws_too_small_sentinel<<<1, 64, 0, stream>>>(out);
    return;
  }

  u16* qb = (u16*)(ws + OFF_Q);
  u16* kb = (u16*)(ws + OFF_K);
  u16* vb = (u16*)(ws + OFF_V);
  float* Fp = (float*)(ws + OFF_FP);
  float* Mc = (float*)(ws + OFF_MC);
  float* Sc = (float*)(ws + OFF_SC);
  u16* Tt = (u16*)(ws + OFF_T);
  u16* Wqb = (u16*)(ws + OFF_WQ);
  u16* Wpb = (u16*)(ws + OFF_WP);
  u16* attn = (u16*)(ws + OFF_V);   // alias: v dead after fpart
  u16* xb = (u16*)d_out;            // alias: d_out scratch, dead before gemm<1> writes

  cast_bf16<<<8192, 256, 0, stream>>>(x, xb, 2097152);          // 16.78M elems
  cast_bf16<<<384, 256, 0, stream>>>(Wqkv, Wqb, 98304);         // 786K
  cast_bf16<<<128, 256, 0, stream>>>(Wproj, Wpb, 32768);        // 262K
  gemm_bt<0><<<dim3(128, 6), 512, 0, stream>>>(xb, Wqb, bqkv, qb, kb, vb, nullptr);
  fpart<<<dim3(NCHUNK, BHN), 256, 0, stream>>>(qb, kb, vb, Fp, Mc, Sc);
  newton_t<<<dim3(BHN), 256, 0, stream>>>(qb, kb, Fp, Mc, Sc, Tt);
  attn_out_k<<<dim3(32, BHN), 256, 0, stream>>>(qb, kb, Tt, attn);
  gemm_bt<1><<<dim3(128, 2), 512, 0, stream>>>(attn, Wpb, bproj, nullptr, nullptr, nullptr, out);
}

// Round 5
// 298.668 us; speedup vs baseline: 1.1986x; 1.1986x over previous
//
#include <hip/hip_runtime.h>

typedef unsigned short u16;
typedef unsigned int u32;

typedef __bf16 v8bf __attribute__((ext_vector_type(8)));
typedef float v4f __attribute__((ext_vector_type(4)));
typedef u16 v8u __attribute__((ext_vector_type(8)));

#define N_TOK 8192
#define CDIM 512
#define HEADS 8
#define HD 64
#define LM 64
#define LSTRIDE 128
#define BHN 32
#define NCHUNK 16
#define SCALE 0.125f

__device__ __forceinline__ float b2f(u16 u) { return __uint_as_float(((u32)u) << 16); }
__device__ __forceinline__ u16 f2bf(float f) {
  u32 u = __float_as_uint(f);
  u += 0x7fffu + ((u >> 16) & 1u);
  return (u16)(u >> 16);
}
__device__ __forceinline__ u32 pk2bf(float a, float b) {
  return (u32)f2bf(a) | ((u32)f2bf(b) << 16);
}

// async global->LDS, 16B per lane. HW dest = wave-uniform base + lane*16.
__device__ __forceinline__ void gl_lds16(const u16* g, u16* l) {
  __builtin_amdgcn_global_load_lds(
      (const __attribute__((address_space(1))) u32*)g,
      (__attribute__((address_space(3))) u32*)l, 16, 0, 0);
}

// hi/lo bf16 split write into swizzled [64][64] u16 panels (chunk ^= row&7).
__device__ __forceinline__ void wr_hl(u16* __restrict__ h, u16* __restrict__ l,
                                      int row, int col, float v) {
  u16 hi = f2bf(v);
  u16 lo = f2bf(v - b2f(hi));
  int a = row * 64 + (((col >> 3) ^ (row & 7)) << 3) + (col & 7);
  h[a] = hi;
  l[a] = lo;
}

// ---------------------------------------------------------------------------
// fp32 -> bf16 cast, 8 elems/thread, fully coalesced.
// ---------------------------------------------------------------------------
__global__ __launch_bounds__(256) void cast_bf16(const float* __restrict__ src,
                                                 u16* __restrict__ dst, int n8) {
  int i = blockIdx.x * 256 + threadIdx.x;
  if (i >= n8) return;
  const float4* s = (const float4*)src;
  float4 a = s[(size_t)i * 2], b = s[(size_t)i * 2 + 1];
  uint4 o;
  o.x = (u32)f2bf(a.x) | ((u32)f2bf(a.y) << 16);
  o.y = (u32)f2bf(a.z) | ((u32)f2bf(a.w) << 16);
  o.z = (u32)f2bf(b.x) | ((u32)f2bf(b.y) << 16);
  o.w = (u32)f2bf(b.z) | ((u32)f2bf(b.w) << 16);
  *(uint4*)(dst + (size_t)i * 8) = o;
}

// ---------------------------------------------------------------------------
// GEMM (R2-proven, 79.6us/51.5GF): 128x128 tile, BK=32, 256 thr,
// global_load_lds(16B) + both-sides involution chunk swizzle. 0 bank conf.
// ---------------------------------------------------------------------------
template <int MODE>
__global__ __launch_bounds__(256) void gemm_bt(const u16* __restrict__ A,
                                               const u16* __restrict__ Bm,
                                               const float* __restrict__ bias,
                                               u16* __restrict__ qo,
                                               u16* __restrict__ ko,
                                               u16* __restrict__ vo,
                                               float* __restrict__ outp) {
  __shared__ __align__(16) u16 As[128 * 32];
  __shared__ __align__(16) u16 Bs[128 * 32];
  const int K = 512;
  const int m0 = blockIdx.x * 128;
  const int n0 = blockIdx.y * 128;
  const int t = threadIdx.x;
  const int lane = t & 63, w = t >> 6;
  const int wm = w >> 1, wn = w & 1;
  const int quad = lane >> 4, lrow = lane & 15;

  v4f acc[4][4];
#pragma unroll
  for (int i = 0; i < 4; ++i)
#pragma unroll
    for (int j = 0; j < 4; ++j)
#pragma unroll
      for (int r = 0; r < 4; ++r) acc[i][j][r] = 0.f;

  for (int kt = 0; kt < K; kt += 32) {
    __syncthreads();
#pragma unroll
    for (int p = 0; p < 2; ++p) {
      int ci = p * 256 + t;
      int r = ci >> 2, s = ci & 3;
      int cs = (s ^ (r >> 1)) & 3;           // inverse-swizzled source chunk
      gl_lds16(A + (size_t)(m0 + r) * K + kt + cs * 8, &As[ci * 8]);
      gl_lds16(Bm + (size_t)(n0 + r) * K + kt + cs * 8, &Bs[ci * 8]);
    }
    __syncthreads();
    v8bf af[4], bf[4];
#pragma unroll
    for (int ti = 0; ti < 4; ++ti) {
      int row = wm * 64 + ti * 16 + lrow;
      af[ti] = *(const v8bf*)&As[row * 32 + ((quad ^ (row >> 1)) & 3) * 8];
    }
#pragma unroll
    for (int tj = 0; tj < 4; ++tj) {
      int row = wn * 64 + tj * 16 + lrow;
      bf[tj] = *(const v8bf*)&Bs[row * 32 + ((quad ^ (row >> 1)) & 3) * 8];
    }
#pragma unroll
    for (int ti = 0; ti < 4; ++ti)
#pragma unroll
      for (int tj = 0; tj < 4; ++tj)
        acc[ti][tj] = __builtin_amdgcn_mfma_f32_16x16x32_bf16(af[ti], bf[tj], acc[ti][tj], 0, 0, 0);
  }

  // epilogue: D layout col=lane&15, row=quad*4+reg (m89/m91-verified)
#pragma unroll
  for (int ti = 0; ti < 4; ++ti) {
#pragma unroll
    for (int tj = 0; tj < 4; ++tj) {
      int gn = n0 + wn * 64 + tj * 16 + lrow;
      float bv = bias[gn];
#pragma unroll
      for (int r = 0; r < 4; ++r) {
        int gm = m0 + wm * 64 + ti * 16 + quad * 4 + r;
        float val = acc[ti][tj][r] + bv;
        if (MODE == 0) {
          int tt = gn >> 9;          // 0=q 1=k 2=v
          int h = (gn >> 6) & 7;
          int d = gn & 63;
          int b = gm >> 13;
          int n = gm & 8191;
          size_t di = ((size_t)(b * HEADS + h) * N_TOK + n) * HD + d;
          u16* dst = (tt == 0) ? qo : (tt == 1) ? ko : vo;
          dst[di] = f2bf(val);
        } else {
          outp[(size_t)gm * CDIM + gn] = val;
        }
      }
    }
  }
}

// ---------------------------------------------------------------------------
// Fused kernel_3 chunk: full MFMA flash (unchanged from R6).
// ---------------------------------------------------------------------------
__global__ __launch_bounds__(256) void fpart(const u16* __restrict__ qb,
                                             const u16* __restrict__ kb,
                                             const u16* __restrict__ vb,
                                             float* __restrict__ Fp,
                                             float* __restrict__ Mc,
                                             float* __restrict__ Sc) {
  __shared__ __align__(16) char smem[4 * 64 * 40 * 2 * 2];   // 40 KiB
  __shared__ float msh[4][64], ssh[4][64];
  const int jc = blockIdx.x, bh = blockIdx.y;
  const int t = threadIdx.x;
  const int lane = t & 63, w = t >> 6;
  const int col = lane & 15, quad = lane >> 4;
  const int jq = lane & 7, dh = lane >> 3;

  u16* Pw = (u16*)smem + w * (64 * 40);
  u16* vT = (u16*)smem + 4 * (64 * 40) + w * (64 * 40);
  float* Fbuf = (float*)smem;

  v8bf qf[4][2];
#pragma unroll
  for (int it = 0; it < 4; ++it)
#pragma unroll
    for (int kh = 0; kh < 2; ++kh)
      qf[it][kh] = *(const v8bf*)(qb + ((size_t)bh * N_TOK + (size_t)(it * 16 + col) * LSTRIDE) * HD + kh * 32 + quad * 8);

  float mw[4], sw[4];
  v4f facc[4][4];   // facc[dt][it][r] = F[it*16+col][dt*16+quad*4+r]
#pragma unroll
  for (int it = 0; it < 4; ++it) { mw[it] = -3.0e38f; sw[it] = 0.f; }
#pragma unroll
  for (int dt = 0; dt < 4; ++dt)
#pragma unroll
    for (int it = 0; it < 4; ++it)
#pragma unroll
      for (int r = 0; r < 4; ++r) facc[dt][it][r] = 0.f;

  for (int st = 0; st < 4; ++st) {
    const int j0 = jc * 512 + w * 128 + st * 32;

    v8bf kf[2][2];
#pragma unroll
    for (int jt = 0; jt < 2; ++jt)
#pragma unroll
      for (int kh = 0; kh < 2; ++kh)
        kf[jt][kh] = *(const v8bf*)(kb + ((size_t)bh * N_TOK + j0 + jt * 16 + col) * HD + kh * 32 + quad * 8);

    v8u r0 = *(const v8u*)(vb + ((size_t)bh * N_TOK + j0 + jq * 4 + 0) * HD + dh * 8);
    v8u r1 = *(const v8u*)(vb + ((size_t)bh * N_TOK + j0 + jq * 4 + 1) * HD + dh * 8);
    v8u r2 = *(const v8u*)(vb + ((size_t)bh * N_TOK + j0 + jq * 4 + 2) * HD + dh * 8);
    v8u r3 = *(const v8u*)(vb + ((size_t)bh * N_TOK + j0 + jq * 4 + 3) * HD + dh * 8);
#pragma unroll
    for (int e = 0; e < 8; ++e) {
      uint2 pk;
      pk.x = (u32)r0[e] | ((u32)r1[e] << 16);
      pk.y = (u32)r2[e] | ((u32)r3[e] << 16);
      *(uint2*)&vT[(dh * 8 + e) * 40 + jq * 4] = pk;
    }

    v4f sacc[2][4];
#pragma unroll
    for (int jt = 0; jt < 2; ++jt)
#pragma unroll
      for (int it = 0; it < 4; ++it) {
#pragma unroll
        for (int r = 0; r < 4; ++r) sacc[jt][it][r] = 0.f;
#pragma unroll
        for (int kh = 0; kh < 2; ++kh)
          sacc[jt][it] = __builtin_amdgcn_mfma_f32_16x16x32_bf16(kf[jt][kh], qf[it][kh], sacc[jt][it], 0, 0, 0);
      }

#pragma unroll
    for (int it = 0; it < 4; ++it) {
      float mloc = -3.0e38f;
#pragma unroll
      for (int jt = 0; jt < 2; ++jt)
#pragma unroll
        for (int r = 0; r < 4; ++r) {
          float s = sacc[jt][it][r] * SCALE;
          sacc[jt][it][r] = s;
          mloc = fmaxf(mloc, s);
        }
      mloc = fmaxf(mloc, __shfl_xor(mloc, 16));
      mloc = fmaxf(mloc, __shfl_xor(mloc, 32));
      float mnew = fmaxf(mw[it], mloc);
      float alpha = __expf(mw[it] - mnew);
      mw[it] = mnew;
      float rs = 0.f;
#pragma unroll
      for (int jt = 0; jt < 2; ++jt)
#pragma unroll
        for (int r = 0; r < 4; ++r) {
          float p = __expf(sacc[jt][it][r] - mnew);
          sacc[jt][it][r] = p;
          rs += p;
        }
      rs += __shfl_xor(rs, 16);
      rs += __shfl_xor(rs, 32);
      sw[it] = sw[it] * alpha + rs;
#pragma unroll
      for (int jt = 0; jt < 2; ++jt) {
        uint2 pk;
        pk.x = pk2bf(sacc[jt][it][0], sacc[jt][it][1]);
        pk.y = pk2bf(sacc[jt][it][2], sacc[jt][it][3]);
        *(uint2*)&Pw[(it * 16 + col) * 40 + jt * 16 + quad * 4] = pk;
      }
#pragma unroll
      for (int dt = 0; dt < 4; ++dt)
#pragma unroll
        for (int r = 0; r < 4; ++r) facc[dt][it][r] *= alpha;
    }

    v8bf vfr[4], pfr[4];
#pragma unroll
    for (int dt = 0; dt < 4; ++dt)
      vfr[dt] = *(const v8bf*)&vT[(dt * 16 + col) * 40 + quad * 8];
#pragma unroll
    for (int it = 0; it < 4; ++it)
      pfr[it] = *(const v8bf*)&Pw[(it * 16 + col) * 40 + quad * 8];
#pragma unroll
    for (int dt = 0; dt < 4; ++dt)
#pragma unroll
      for (int it = 0; it < 4; ++it)
        facc[dt][it] = __builtin_amdgcn_mfma_f32_16x16x32_bf16(vfr[dt], pfr[it], facc[dt][it], 0, 0, 0);
  }

  if (quad == 0) {
#pragma unroll
    for (int it = 0; it < 4; ++it) {
      msh[w][it * 16 + col] = mw[it];
      ssh[w][it * 16 + col] = sw[it];
    }
  }
  __syncthreads();

  const size_t cb = (size_t)(bh * NCHUNK + jc) * 64;
  float scl[4];
#pragma unroll
  for (int it = 0; it < 4; ++it) {
    int i = it * 16 + col;
    float m0 = msh[0][i], m1 = msh[1][i], m2 = msh[2][i], m3 = msh[3][i];
    float M = fmaxf(fmaxf(m0, m1), fmaxf(m2, m3));
    float e0 = __expf(m0 - M), e1 = __expf(m1 - M);
    float e2 = __expf(m2 - M), e3 = __expf(m3 - M);
    float Stot = e0 * ssh[0][i] + e1 * ssh[1][i] + e2 * ssh[2][i] + e3 * ssh[3][i];
    scl[it] = (w == 0) ? e0 : (w == 1) ? e1 : (w == 2) ? e2 : e3;
    if (w == 0 && quad == 0) {
      Mc[cb + i] = M;
      Sc[cb + i] = Stot;
    }
  }

  for (int wv = 0; wv < 4; ++wv) {
    if (w == wv) {
#pragma unroll
      for (int it = 0; it < 4; ++it)
#pragma unroll
        for (int dt = 0; dt < 4; ++dt) {
          float* dst = &Fbuf[(it * 16 + col) * 76 + dt * 16 + quad * 4];
          float4 v;
          v.x = facc[dt][it][0] * scl[it];
          v.y = facc[dt][it][1] * scl[it];
          v.z = facc[dt][it][2] * scl[it];
          v.w = facc[dt][it][3] * scl[it];
          if (wv == 0) {
            *(float4*)dst = v;
          } else {
            float4 o = *(float4*)dst;
            o.x += v.x; o.y += v.y; o.z += v.z; o.w += v.w;
            *(float4*)dst = o;
          }
        }
    }
    __syncthreads();
  }

  size_t base = (size_t)(bh * NCHUNK + jc) * 4096;
#pragma unroll
  for (int p = 0; p < 16; ++p) {
    int idx = p * 256 + t;
    Fp[base + idx] = Fbuf[(idx >> 6) * 76 + (idx & 63)];
  }
}

// ---------------------------------------------------------------------------
// newton_t R10: all 13 matmuls via MFMA with bf16 hi/lo split (3-product
// fp32-precision trick; missing lo*lo ~2^-18 rel). Z kept in registers at
// D-layout across iterations. LDS panels [64][64] u16, swizzled chunk^row&7:
//   mT (M^T, staged once), z (Z rows), zT (Z^T rows), w (W rows / Fc^T).
// Per iteration: W=mfma(z,mT); P=mfma(w,zT); Zn=2Z-P (regs); write z,zT.
// S = q@k^T from global bf16 frags; T = Z@Fc via Fc^T staged hi/lo.
// 3 barriers/iter; ~320 MFMA/wave total.
// ---------------------------------------------------------------------------
__device__ __forceinline__ void mm_hl(const u16* __restrict__ Ah,
                                      const u16* __restrict__ Al,
                                      const u16* __restrict__ Bh,
                                      const u16* __restrict__ Bl,
                                      int Ra, int quad, int lrow, v4f out[4]) {
  v8bf ah[2], al[2];
#pragma unroll
  for (int kk = 0; kk < 2; ++kk) {
    int c8 = (((kk * 4 + quad) ^ (Ra & 7)) * 8);
    ah[kk] = *(const v8bf*)&Ah[Ra * 64 + c8];
    al[kk] = *(const v8bf*)&Al[Ra * 64 + c8];
  }
#pragma unroll
  for (int nt = 0; nt < 4; ++nt) {
    int Rb = nt * 16 + lrow;
#pragma unroll
    for (int kk = 0; kk < 2; ++kk) {
      int c8 = (((kk * 4 + quad) ^ (Rb & 7)) * 8);
      v8bf bh = *(const v8bf*)&Bh[Rb * 64 + c8];
      v8bf bl = *(const v8bf*)&Bl[Rb * 64 + c8];
      out[nt] = __builtin_amdgcn_mfma_f32_16x16x32_bf16(ah[kk], bh, out[nt], 0, 0, 0);
      out[nt] = __builtin_amdgcn_mfma_f32_16x16x32_bf16(ah[kk], bl, out[nt], 0, 0, 0);
      out[nt] = __builtin_amdgcn_mfma_f32_16x16x32_bf16(al[kk], bh, out[nt], 0, 0, 0);
    }
  }
}

__global__ __launch_bounds__(256) void newton_t(const u16* __restrict__ qb,
                                                const u16* __restrict__ kb,
                                                const float* __restrict__ Fp,
                                                const float* __restrict__ Mc,
                                                const float* __restrict__ Sc,
                                                u16* __restrict__ Tt) {
  __shared__ float Sf[4096];
  __shared__ float red[4];
  __shared__ __align__(16) u16 mTh[4096], mTl[4096];
  __shared__ __align__(16) u16 zh_[4096], zl_[4096];
  __shared__ __align__(16) u16 zTh[4096], zTl[4096];
  __shared__ __align__(16) u16 wh_[4096], wl_[4096];
  const int bh = blockIdx.x;
  const int t = threadIdx.x, lane = t & 63, w = t >> 6;
  const int quad = lane >> 4, lrow = lane & 15;
  const int Ra = w * 16 + lrow;       // A/B-frag row for this wave's m-tile
  const int Rd = w * 16 + quad * 4;   // D-layout row base

  // ---- S = q_lm @ k_lm^T * SCALE (MFMA, bf16 inputs exact) ----
  {
    v8bf qf[2], kf[4][2];
#pragma unroll
    for (int kk = 0; kk < 2; ++kk)
      qf[kk] = *(const v8bf*)(qb + ((size_t)bh * N_TOK + (size_t)Ra * LSTRIDE) * HD + kk * 32 + quad * 8);
#pragma unroll
    for (int nt = 0; nt < 4; ++nt)
#pragma unroll
      for (int kk = 0; kk < 2; ++kk)
        kf[nt][kk] = *(const v8bf*)(kb + ((size_t)bh * N_TOK + (size_t)(nt * 16 + lrow) * LSTRIDE) * HD + kk * 32 + quad * 8);
    v4f sa[4];
#pragma unroll
    for (int nt = 0; nt < 4; ++nt) {
#pragma unroll
      for (int r = 0; r < 4; ++r) sa[nt][r] = 0.f;
#pragma unroll
      for (int kk = 0; kk < 2; ++kk)
        sa[nt] = __builtin_amdgcn_mfma_f32_16x16x32_bf16(qf[kk], kf[nt][kk], sa[nt], 0, 0, 0);
    }
#pragma unroll
    for (int nt = 0; nt < 4; ++nt)
#pragma unroll
      for (int r = 0; r < 4; ++r)
        Sf[(Rd + r) * 64 + nt * 16 + lrow] = sa[nt][r] * SCALE;
  }
  __syncthreads();

  // ---- row softmax (fp32, expf for max fidelity) ----
  for (int rr = 0; rr < 16; ++rr) {
    int i = w * 16 + rr;
    float vv = Sf[i * 64 + lane];
    float m = vv;
#pragma unroll
    for (int off = 32; off; off >>= 1) m = fmaxf(m, __shfl_xor(m, off));
    float e = expf(vv - m);
    float s = e;
#pragma unroll
    for (int off = 32; off; off >>= 1) s += __shfl_xor(s, off);
    Sf[i * 64 + lane] = e / s;
  }
  __syncthreads();

  // ---- Frobenius^2 ----
  float loc = 0.f;
#pragma unroll
  for (int p = 0; p < 16; ++p) {
    float v = Sf[p * 256 + t];
    loc += v * v;
  }
#pragma unroll
  for (int off = 32; off; off >>= 1) loc += __shfl_xor(loc, off);
  if (lane == 0) red[w] = loc;
  __syncthreads();
  float fro = fmaxf(sqrtf(red[0] + red[1] + red[2] + red[3]), 1e-6f);
  float inv = 1.0f / (fro * fro);

  // ---- stage mT, z0, z0T hi/lo; init z_reg at D layout ----
  for (int p = 0; p < 16; ++p) {
    int idx = p * 256 + t;
    int r = idx >> 6, c = idx & 63;
    float Mrc = Sf[r * 64 + c];   // M[r][c]
    float Mcr = Sf[c * 64 + r];   // M[c][r]
    wr_hl(mTh, mTl, r, c, Mcr);          // mT = M^T
    wr_hl(zh_, zl_, r, c, Mcr * inv);    // z  = M^T/fro^2
    wr_hl(zTh, zTl, r, c, Mrc * inv);    // zT = M/fro^2
  }
  float zr[4][4];
#pragma unroll
  for (int nt = 0; nt < 4; ++nt)
#pragma unroll
    for (int r = 0; r < 4; ++r)
      zr[nt][r] = Sf[(nt * 16 + lrow) * 64 + Rd + r] * inv;
  __syncthreads();

  // ---- 6 Newton-Schulz iterations ----
  for (int it = 0; it < 6; ++it) {
    v4f aw[4];
#pragma unroll
    for (int nt = 0; nt < 4; ++nt)
#pragma unroll
      for (int r = 0; r < 4; ++r) aw[nt][r] = 0.f;
    mm_hl(zh_, zl_, mTh, mTl, Ra, quad, lrow, aw);   // W = Z@M
#pragma unroll
    for (int nt = 0; nt < 4; ++nt)
#pragma unroll
      for (int r = 0; r < 4; ++r)
        wr_hl(wh_, wl_, Rd + r, nt * 16 + lrow, aw[nt][r]);
    __syncthreads();

    v4f ap[4];
#pragma unroll
    for (int nt = 0; nt < 4; ++nt)
#pragma unroll
      for (int r = 0; r < 4; ++r) ap[nt][r] = 0.f;
    mm_hl(wh_, wl_, zTh, zTl, Ra, quad, lrow, ap);   // P = W@Z
    float znr[4][4];
#pragma unroll
    for (int nt = 0; nt < 4; ++nt)
#pragma unroll
      for (int r = 0; r < 4; ++r)
        znr[nt][r] = 2.f * zr[nt][r] - ap[nt][r];
    __syncthreads();   // all zT reads complete before overwrite

#pragma unroll
    for (int nt = 0; nt < 4; ++nt)
#pragma unroll
      for (int r = 0; r < 4; ++r) {
        zr[nt][r] = znr[nt][r];
        wr_hl(zh_, zl_, Rd + r, nt * 16 + lrow, znr[nt][r]);
        wr_hl(zTh, zTl, nt * 16 + lrow, Rd + r, znr[nt][r]);
      }
    __syncthreads();
  }

  // ---- chunk combine weights into Sf (dead) ----
  if (t < 64) {
    float M = -3.0e38f;
#pragma unroll
    for (int jc = 0; jc < NCHUNK; ++jc)
      M = fmaxf(M, Mc[(bh * NCHUNK + jc) * 64 + t]);
    float S = 0.f;
#pragma unroll
    for (int jc = 0; jc < NCHUNK; ++jc)
      S += expf(Mc[(bh * NCHUNK + jc) * 64 + t] - M) * Sc[(bh * NCHUNK + jc) * 64 + t];
    float invS = 1.0f / S;
#pragma unroll
    for (int jc = 0; jc < NCHUNK; ++jc)
      Sf[jc * 64 + t] = expf(Mc[(bh * NCHUNK + jc) * 64 + t] - M) * invS;
  }
  __syncthreads();

  // ---- Fc^T hi/lo into w panels (dead after last matmul2) ----
  for (int p = 0; p < 16; ++p) {
    int idx = p * 256 + t;
    int i = idx >> 6, d = idx & 63;
    float sum = 0.f;
#pragma unroll
    for (int jc = 0; jc < NCHUNK; ++jc)
      sum += Sf[jc * 64 + i] * Fp[(size_t)(bh * NCHUNK + jc) * 4096 + idx];
    wr_hl(wh_, wl_, d, i, sum);
  }
  __syncthreads();

  // ---- T = Z @ Fc; write Tt[bh][d][j] bf16 ----
  v4f at[4];
#pragma unroll
  for (int nt = 0; nt < 4; ++nt)
#pragma unroll
    for (int r = 0; r < 4; ++r) at[nt][r] = 0.f;
  mm_hl(zh_, zl_, wh_, wl_, Ra, quad, lrow, at);
#pragma unroll
  for (int nt = 0; nt < 4; ++nt)
#pragma unroll
    for (int r = 0; r < 4; ++r)
      Tt[(size_t)bh * 4096 + (size_t)(nt * 16 + lrow) * 64 + (Rd + r)] = f2bf(at[nt][r]);
}

// ---------------------------------------------------------------------------
// MFMA attn_out (unchanged): S^T = klm@q^T, in-register softmax,
// P via per-wave swizzled LDS, out = P@Tt.
// ---------------------------------------------------------------------------
__global__ __launch_bounds__(256) void attn_out_k(const u16* __restrict__ qb,
                                                  const u16* __restrict__ kb,
                                                  const u16* __restrict__ Tt,
                                                  u16* __restrict__ ao) {
  __shared__ __align__(16) u16 Pl[4][1024];
  const int bh = blockIdx.y;
  const int b = bh >> 3, h = bh & 7;
  const int t = threadIdx.x;
  const int lane = t & 63, w = t >> 6;
  const int col = lane & 15, quad = lane >> 4;
  const int rot = (col & 7) * 8;

  v8bf kfr[4][2], tfr[4][2];
#pragma unroll
  for (int tj = 0; tj < 4; ++tj)
#pragma unroll
    for (int kh = 0; kh < 2; ++kh)
      kfr[tj][kh] = *(const v8bf*)(kb + ((size_t)bh * N_TOK + (size_t)(tj * 16 + col) * LSTRIDE) * HD + kh * 32 + quad * 8);
#pragma unroll
  for (int td = 0; td < 4; ++td)
#pragma unroll
    for (int jh = 0; jh < 2; ++jh)
      tfr[td][jh] = *(const v8bf*)(Tt + (size_t)bh * 4096 + (size_t)(td * 16 + col) * 64 + jh * 32 + quad * 8);

  u16* Pw = &Pl[w][0];

  for (int tile = 0; tile < 4; ++tile) {
    const int n0 = blockIdx.x * 256 + w * 64 + tile * 16;
    v8bf qf[2];
#pragma unroll
    for (int kh = 0; kh < 2; ++kh)
      qf[kh] = *(const v8bf*)(qb + ((size_t)bh * N_TOK + n0 + col) * HD + kh * 32 + quad * 8);

    v4f S[4];
#pragma unroll
    for (int tj = 0; tj < 4; ++tj) {
#pragma unroll
      for (int r = 0; r < 4; ++r) S[tj][r] = 0.f;
#pragma unroll
      for (int kh = 0; kh < 2; ++kh)
        S[tj] = __builtin_amdgcn_mfma_f32_16x16x32_bf16(kfr[tj][kh], qf[kh], S[tj], 0, 0, 0);
    }

    float mx = -3.0e38f;
#pragma unroll
    for (int tj = 0; tj < 4; ++tj)
#pragma unroll
      for (int r = 0; r < 4; ++r) {
        S[tj][r] *= SCALE;
        mx = fmaxf(mx, S[tj][r]);
      }
    mx = fmaxf(mx, __shfl_xor(mx, 16));
    mx = fmaxf(mx, __shfl_xor(mx, 32));
    float sum = 0.f;
#pragma unroll
    for (int tj = 0; tj < 4; ++tj)
#pragma unroll
      for (int r = 0; r < 4; ++r) {
        S[tj][r] = __expf(S[tj][r] - mx);
        sum += S[tj][r];
      }
    sum += __shfl_xor(sum, 16);
    sum += __shfl_xor(sum, 32);
    float inv = 1.0f / sum;

#pragma unroll
    for (int tj = 0; tj < 4; ++tj) {
      u32 lo = (u32)f2bf(S[tj][0] * inv) | ((u32)f2bf(S[tj][1] * inv) << 16);
      u32 hi = (u32)f2bf(S[tj][2] * inv) | ((u32)f2bf(S[tj][3] * inv) << 16);
      uint2 pk = {lo, hi};
      *(uint2*)&Pw[col * 64 + ((tj * 16 + quad * 4 + rot) & 63)] = pk;
    }
    v8bf pf[2];
#pragma unroll
    for (int jh = 0; jh < 2; ++jh)
      pf[jh] = *(const v8bf*)&Pw[col * 64 + ((jh * 32 + quad * 8 + rot) & 63)];

    v4f O[4];
#pragma unroll
    for (int td = 0; td < 4; ++td) {
#pragma unroll
      for (int r = 0; r < 4; ++r) O[td][r] = 0.f;
#pragma unroll
      for (int jh = 0; jh < 2; ++jh)
        O[td] = __builtin_amdgcn_mfma_f32_16x16x32_bf16(pf[jh], tfr[td][jh], O[td], 0, 0, 0);
    }
#pragma unroll
    for (int td = 0; td < 4; ++td)
#pragma unroll
      for (int r = 0; r < 4; ++r) {
        int n = n0 + quad * 4 + r;
        ao[((size_t)(b * N_TOK + n)) * CDIM + h * HD + td * 16 + col] = f2bf(O[td][r]);
      }
  }
}

__global__ void ws_too_small_sentinel(float* out) {
  if (threadIdx.x == 0 && blockIdx.x == 0) out[0] = 1.0f;
}

// ---------------------------------------------------------------------------
// Workspace: q/k/v bf16 (96 MiB), Fp fp32 8 MiB, Mc/Sc/Tt small, Wqkv/Wproj
// bf16 casts (+2 MiB). x_bf16 lives in d_out (dead until gemm1). ~107 MiB.
// ---------------------------------------------------------------------------
static constexpr size_t SZ_QKV = (size_t)BHN * N_TOK * HD * 2;        // 32 MiB
static constexpr size_t OFF_Q = 0;
static constexpr size_t OFF_K = OFF_Q + SZ_QKV;
static constexpr size_t OFF_V = OFF_K + SZ_QKV;
static constexpr size_t OFF_FP = OFF_V + SZ_QKV;
static constexpr size_t SZ_FP = (size_t)BHN * NCHUNK * 4096 * 4;      // 8 MiB
static constexpr size_t OFF_MC = OFF_FP + SZ_FP;
static constexpr size_t SZ_MS = (size_t)BHN * NCHUNK * 64 * 4;        // 128 KiB
static constexpr size_t OFF_SC = OFF_MC + SZ_MS;
static constexpr size_t OFF_T = OFF_SC + SZ_MS;
static constexpr size_t OFF_WQ = OFF_T + (size_t)BHN * 4096 * 2;      // Tt 256 KiB
static constexpr size_t OFF_WP = OFF_WQ + (size_t)3 * CDIM * CDIM * 2;  // Wqkv bf16 1.5 MiB
static constexpr size_t OFF_END = OFF_WP + (size_t)CDIM * CDIM * 2;     // +0.5 MiB

extern "C" void kernel_launch(void* const* d_in, const int* in_sizes, int n_in,
                              void* d_out, int out_size, void* d_ws, size_t ws_size,
                              hipStream_t stream) {
  const float* x = (const float*)d_in[0];
  const float* Wqkv = (const float*)d_in[1];
  const float* bqkv = (const float*)d_in[2];
  const float* Wproj = (const float*)d_in[3];
  const float* bproj = (const float*)d_in[4];
  float* out = (float*)d_out;
  char* ws = (char*)d_ws;
  if (ws_size < OFF_END) {
    ws_too_small_sentinel<<<1, 64, 0, stream>>>(out);
    return;
  }

  u16* qb = (u16*)(ws + OFF_Q);
  u16* kb = (u16*)(ws + OFF_K);
  u16* vb = (u16*)(ws + OFF_V);
  float* Fp = (float*)(ws + OFF_FP);
  float* Mc = (float*)(ws + OFF_MC);
  float* Sc = (float*)(ws + OFF_SC);
  u16* Tt = (u16*)(ws + OFF_T);
  u16* Wqb = (u16*)(ws + OFF_WQ);
  u16* Wpb = (u16*)(ws + OFF_WP);
  u16* attn = (u16*)(ws + OFF_V);   // alias: v dead after fpart
  u16* xb = (u16*)d_out;            // alias: d_out scratch, dead before gemm<1> writes

  cast_bf16<<<8192, 256, 0, stream>>>(x, xb, 2097152);          // 16.78M elems
  cast_bf16<<<384, 256, 0, stream>>>(Wqkv, Wqb, 98304);         // 786K
  cast_bf16<<<128, 256, 0, stream>>>(Wproj, Wpb, 32768);        // 262K
  gemm_bt<0><<<dim3(256, 12), 256, 0, stream>>>(xb, Wqb, bqkv, qb, kb, vb, nullptr);
  fpart<<<dim3(NCHUNK, BHN), 256, 0, stream>>>(qb, kb, vb, Fp, Mc, Sc);
  newton_t<<<dim3(BHN), 256, 0, stream>>>(qb, kb, Fp, Mc, Sc, Tt);
  attn_out_k<<<dim3(32, BHN), 256, 0, stream>>>(qb, kb, Tt, attn);
  gemm_bt<1><<<dim3(256, 4), 256, 0, stream>>>(attn, Wpb, bproj, nullptr, nullptr, nullptr, out);
}